// Round 13
// baseline (1565.576 us; speedup 1.0000x reference)
//
#include <hip/hip_runtime.h>
#include <hip/hip_bf16.h>
#include <math.h>

#define DEV __device__ __forceinline__

DEV float sigmoidf_(float x) { return 1.0f / (1.0f + __expf(-x)); }

#define R10(OP) OP(0) OP(1) OP(2) OP(3) OP(4) OP(5) OP(6) OP(7) OP(8) OP(9)
#define R11(OP) R10(OP) OP(10)

// dot of sA[base..base+9] with hO scalars (sA entries are wave-uniform)
#define DOT_O(base) (sA[(base)+0]*hO0 + sA[(base)+1]*hO1 + sA[(base)+2]*hO2 + sA[(base)+3]*hO3 \
                   + sA[(base)+4]*hO4 + sA[(base)+5]*hO5 + sA[(base)+6]*hO6 + sA[(base)+7]*hO7 \
                   + sA[(base)+8]*hO8 + sA[(base)+9]*hO9)
#define DOT_D(base) (sA[(base)+0]*hD0 + sA[(base)+1]*hD1 + sA[(base)+2]*hD2 + sA[(base)+3]*hD3 \
                   + sA[(base)+4]*hD4 + sA[(base)+5]*hD5 + sA[(base)+6]*hD6 + sA[(base)+7]*hD7 \
                   + sA[(base)+8]*hD8 + sA[(base)+9]*hD9 + sA[(base)+10]*hD10)

DEV float gstep(float x, float h, const float* k, const float* rk, const float* bb) {
  const float z  = sigmoidf_(fmaf(x, k[0], bb[0]) + fmaf(h, rk[0], bb[3]));
  const float r  = sigmoidf_(fmaf(x, k[1], bb[1]) + fmaf(h, rk[1], bb[4]));
  const float hh = tanhf(fmaf(x, k[2], bb[2]) + r * fmaf(h, rk[2], bb[5]));
  return z * h + (1.f - z) * hh;
}

// 3 tiny sequential bidirectional GRU chains + softmax + gather -> tp[3][60]
__global__ void __launch_bounds__(64, 1)
temporal_kernel(const float* __restrict__ T, const float* __restrict__ GK,
                const float* __restrict__ GRK, const float* __restrict__ GB,
                const float* __restrict__ WO, const int* __restrict__ IDX,
                float* __restrict__ tp) {
  const int i = threadIdx.x;
  __shared__ float fb[3][75];
  __shared__ float gg[3][75];
  if (i < 3) {
    float k0[3], k1[3], rk0[3], rk1[3];
#pragma unroll
    for (int q = 0; q < 3; ++q) {
      k0[q]  = GK[i * 6 + q];      k1[q]  = GK[i * 6 + 3 + q];
      rk0[q] = GRK[i * 6 + q];     rk1[q] = GRK[i * 6 + 3 + q];
    }
    const float* B0 = GB + i * 12;
    const float* B1 = GB + i * 12 + 6;
    float h = 0.f;
    for (int s = 0; s < 75; ++s) { h = gstep(T[i * 75 + s], h, k0, rk0, B0); fb[i][s] = h; }
    h = 0.f;
    for (int s = 0; s < 75; ++s) { h = gstep(fb[i][74 - s], h, k1, rk1, B1); gg[i][s] = h; }
    const float wo = WO[i];
    float mx = -1e30f;
    for (int s = 0; s < 75; ++s) mx = fmaxf(mx, gg[i][s] * wo);
    float sum = 0.f;
    for (int s = 0; s < 75; ++s) { const float e = __expf(gg[i][s] * wo - mx); fb[i][s] = e; sum += e; }
    const float inv = 1.f / sum;
    for (int j = 0; j < 60; ++j) tp[i * 60 + j] = fb[i][IDX[j]] * inv;
  }
}

// Weight repack: W[K x 64] -> PK[K/4][64][4] so lane c vector-loads its 4
// consecutive k-values as ONE coalesced global_load_dwordx4 (was 4 scalar
// loads 256B apart + 4 addr calcs — ~45% of the round-12 instruction stream).
// k4-block layout in ws (1KB each): ZR[0..31] RR[32..63] MR[64..95]
// ZO[96..143] RO[144..191] MO[192..239] ZD[240..271] RD[272..303] MD[304..335]
__global__ void __launch_bounds__(64, 1) prep_kernel(
    const float* __restrict__ WzR, const float* __restrict__ WrR, const float* __restrict__ WmR,
    const float* __restrict__ WzO, const float* __restrict__ WrO, const float* __restrict__ WmO,
    const float* __restrict__ WzD, const float* __restrict__ WrD, const float* __restrict__ WmD,
    char* __restrict__ ws) {
  const int fi = blockIdx.x;
  const int c = threadIdx.x;
  const float* W; int base;
  if      (fi <  32) { W = WzR; base = 0;   }
  else if (fi <  64) { W = WrR; base = 32;  }
  else if (fi <  96) { W = WmR; base = 64;  }
  else if (fi < 144) { W = WzO; base = 96;  }
  else if (fi < 192) { W = WrO; base = 144; }
  else if (fi < 240) { W = WmO; base = 192; }
  else if (fi < 272) { W = WzD; base = 240; }
  else if (fi < 304) { W = WrD; base = 272; }
  else               { W = WmD; base = 304; }
  const int kb = fi - base;
  float4 v;
  v.x = W[(kb * 4 + 0) * 64 + c];
  v.y = W[(kb * 4 + 1) * 64 + c];
  v.z = W[(kb * 4 + 2) * 64 + c];
  v.w = W[(kb * 4 + 3) * 64 + c];
  *(float4*)(ws + 1024 + (size_t)fi * 1024 + c * 16) = v;
}

// 4 waves per 256-thread WG; wave-private LDS slices; NO __syncthreads and
// NO divergent early-return (present in every spilling multi-wave round,
// absent in every clean 64-thr round — b is clamped instead).
// Body = proven R8 shape (whole-gate accumulators, time-shared staging):
//   phase A: gate O uses sm[0..1919]  (10 x 192)
//   phase B: gates D (11 x 128, sm[0..1407]) + R (sm[1408..1535])
__global__ void __launch_bounds__(256, 2) ggnn_main(
    const float* __restrict__ X, const float* __restrict__ A,
    const float* __restrict__ WgR, const float* __restrict__ bgR,
    const float* __restrict__ WgO, const float* __restrict__ bgO,
    const float* __restrict__ WgD, const float* __restrict__ bgD,
    const float* __restrict__ bmR, const float* __restrict__ bmO, const float* __restrict__ bmD,
    const float* __restrict__ W1R, const float* __restrict__ b1R, const float* __restrict__ W2R,
    const float* __restrict__ W1O, const float* __restrict__ b1O, const float* __restrict__ W2O,
    const float* __restrict__ W1D, const float* __restrict__ b1D, const float* __restrict__ W2D,
    const char* __restrict__ ws, const float* __restrict__ tp, int B,
    float* __restrict__ out) {
  const int w = threadIdx.x >> 6;   // wave 0..3
  const int c = threadIdx.x & 63;   // lane = feature column
  int b = blockIdx.x * 4 + w;
  if (b >= B) b = B - 1;            // clamp, no divergent return

  // packed weight bases (float4 per (kb, c))
  const float4* pk = (const float4*)(ws + 1024);
  const float4* pWzR = pk + 0   * 64;
  const float4* pWrR = pk + 32  * 64;
  const float4* pWmR = pk + 64  * 64;
  const float4* pWzO = pk + 96  * 64;
  const float4* pWrO = pk + 144 * 64;
  const float4* pWmO = pk + 192 * 64;
  const float4* pWzD = pk + 240 * 64;
  const float4* pWrD = pk + 272 * 64;
  const float4* pWmD = pk + 304 * 64;

  __shared__ __align__(16) float smemAll[4 * 1920];
  __shared__ float sAAll[4 * 484];
  float* sm = smemAll + w * 1920;
  const float* sA = sAAll + w * 484;

  const float* Xb = X + (size_t)b * 880;
  const float* Ab = A + (size_t)b * 484;
  for (int t = c; t < 880; t += 64) sm[t] = Xb[t];
  { float* sw = sAAll + w * 484;
    for (int t = c; t < 484; t += 64) sw[t] = Ab[t]; }

  // ---------------- phase 0: h = tanh(Xg @ Wg + bg) ----------------
  float hR;
#define DECLHO(i) float hO##i;
  R10(DECLHO)
#undef DECLHO
#define DECLHD(i) float hD##i;
  R11(DECLHD)
#undef DECLHD
  {
    float aR = bgR[c], cO = bgO[c], cD = bgD[c];
#pragma unroll 4
    for (int k = 0; k < 40; ++k) {
      const float x = sm[k];
      aR = fmaf(x, WgR[k * 64 + c], aR);
      cO = fmaf(x, WgO[k * 64 + c], cO);
      cD = fmaf(x, WgD[k * 64 + c], cD);
    }
    hR = tanhf(aR);
#define DECLAO(i) float aO##i = cO;
    R10(DECLAO)
#undef DECLAO
#define DECLAD(i) float aD##i = cD;
    R11(DECLAD)
#undef DECLAD
#pragma unroll 2
    for (int k = 0; k < 30; ++k) {
      const float wo_ = WgO[(40 + k) * 64 + c];
      const float wd_ = WgD[(40 + k) * 64 + c];
#define AOSTEP(i) aO##i = fmaf(sm[(1 + i) * 40 + 10 + k], wo_, aO##i);
      R10(AOSTEP)
#undef AOSTEP
#define ADSTEP(i) aD##i = fmaf(sm[(11 + i) * 40 + 10 + k], wd_, aD##i);
      R11(ADSTEP)
#undef ADSTEP
    }
#define TANHO(i) hO##i = tanhf(aO##i);
    R10(TANHO)
#undef TANHO
#define TANHD(i) hD##i = tanhf(aD##i);
    R11(TANHD)
#undef TANHD
  }

  const float bmOc = bmO[c], bmDc = bmD[c], bmRc = bmR[c];

  // ---------------- 3 GRU iterations ----------------
  for (int it = 0; it < 3; ++it) {
    // snapshot messages depending on OLD hO (gate O overwrites hO)
    const float nR = DOT_O(1);
#define DECLND(i) const float nD##i = DOT_O((11 + i) * 22 + 1);
    R11(DECLND)
#undef DECLND

    // ---- phase A: gate O (10 rows, K=192) ----
#define STAGEO(i) sm[i * 192 + c] = hO##i; \
                  sm[i * 192 + 64 + c] = sA[(1 + i) * 22] * hR; \
                  sm[i * 192 + 128 + c] = DOT_D((1 + i) * 22 + 11);
    R10(STAGEO)
#undef STAGEO
    {
#define DECLZR(i) float az##i = 0.f, ar##i = 0.f;
      R10(DECLZR)
#undef DECLZR
#pragma unroll 2
      for (int kb = 0; kb < 48; ++kb) {
        const float4 wz = pWzO[kb * 64 + c];
        const float4 wr = pWrO[kb * 64 + c];
#define MSTEP(i) { const float4 v = *reinterpret_cast<const float4*>(&sm[i * 192 + kb * 4]); \
        az##i = fmaf(v.x, wz.x, az##i); az##i = fmaf(v.y, wz.y, az##i); \
        az##i = fmaf(v.z, wz.z, az##i); az##i = fmaf(v.w, wz.w, az##i); \
        ar##i = fmaf(v.x, wr.x, ar##i); ar##i = fmaf(v.y, wr.y, ar##i); \
        ar##i = fmaf(v.z, wr.z, ar##i); ar##i = fmaf(v.w, wr.w, ar##i); }
        R10(MSTEP)
#undef MSTEP
      }
#define SIGZR(i) const float z##i = sigmoidf_(az##i); const float r##i = sigmoidf_(ar##i);
      R10(SIGZR)
#undef SIGZR
#define STAGEHR(i) sm[i * 192 + c] = hO##i * r##i;
      R10(STAGEHR)
#undef STAGEHR
#define DECLAM(i) float am##i = bmOc;
      R10(DECLAM)
#undef DECLAM
#pragma unroll 2
      for (int kb = 0; kb < 48; ++kb) {
        const float4 wm = pWmO[kb * 64 + c];
#define MSTEP(i) { const float4 v = *reinterpret_cast<const float4*>(&sm[i * 192 + kb * 4]); \
        am##i = fmaf(v.x, wm.x, am##i); am##i = fmaf(v.y, wm.y, am##i); \
        am##i = fmaf(v.z, wm.z, am##i); am##i = fmaf(v.w, wm.w, am##i); }
        R10(MSTEP)
#undef MSTEP
      }
#define UPDO(i) hO##i = (1.f - z##i) * hO##i + z##i * tanhf(am##i);
      R10(UPDO)
#undef UPDO
    }

    // ---- phase B: gates D (11 rows, K=128) + R ----
#define STAGEDD(i) sm[i * 128 + c] = hD##i; \
                   sm[i * 128 + 64 + c] = nD##i;
    R11(STAGEDD)
#undef STAGEDD
    sm[1408 + c] = hR;
    sm[1472 + c] = nR;
    {
#define DECLZR(i) float az##i = 0.f, ar##i = 0.f;
      R11(DECLZR)
#undef DECLZR
      float azR = 0.f, arR = 0.f;
#pragma unroll 2
      for (int kb = 0; kb < 32; ++kb) {
        const float4 wz = pWzD[kb * 64 + c];
        const float4 wr = pWrD[kb * 64 + c];
#define MSTEP(i) { const float4 v = *reinterpret_cast<const float4*>(&sm[i * 128 + kb * 4]); \
        az##i = fmaf(v.x, wz.x, az##i); az##i = fmaf(v.y, wz.y, az##i); \
        az##i = fmaf(v.z, wz.z, az##i); az##i = fmaf(v.w, wz.w, az##i); \
        ar##i = fmaf(v.x, wr.x, ar##i); ar##i = fmaf(v.y, wr.y, ar##i); \
        ar##i = fmaf(v.z, wr.z, ar##i); ar##i = fmaf(v.w, wr.w, ar##i); }
        R11(MSTEP)
#undef MSTEP
        const float4 wzr = pWzR[kb * 64 + c];
        const float4 wrr = pWrR[kb * 64 + c];
        const float4 vr = *reinterpret_cast<const float4*>(&sm[1408 + kb * 4]);
        azR = fmaf(vr.x, wzr.x, azR); azR = fmaf(vr.y, wzr.y, azR);
        azR = fmaf(vr.z, wzr.z, azR); azR = fmaf(vr.w, wzr.w, azR);
        arR = fmaf(vr.x, wrr.x, arR); arR = fmaf(vr.y, wrr.y, arR);
        arR = fmaf(vr.z, wrr.z, arR); arR = fmaf(vr.w, wrr.w, arR);
      }
#define SIGZR(i) const float z##i = sigmoidf_(az##i); const float r##i = sigmoidf_(ar##i);
      R11(SIGZR)
#undef SIGZR
      const float zR_ = sigmoidf_(azR);
      const float rR_ = sigmoidf_(arR);
#define STAGEHR(i) sm[i * 128 + c] = hD##i * r##i;
      R11(STAGEHR)
#undef STAGEHR
      sm[1408 + c] = hR * rR_;
#define DECLAM(i) float am##i = bmDc;
      R11(DECLAM)
#undef DECLAM
      float amR = bmRc;
#pragma unroll 2
      for (int kb = 0; kb < 32; ++kb) {
        const float4 wm = pWmD[kb * 64 + c];
#define MSTEP(i) { const float4 v = *reinterpret_cast<const float4*>(&sm[i * 128 + kb * 4]); \
        am##i = fmaf(v.x, wm.x, am##i); am##i = fmaf(v.y, wm.y, am##i); \
        am##i = fmaf(v.z, wm.z, am##i); am##i = fmaf(v.w, wm.w, am##i); }
        R11(MSTEP)
#undef MSTEP
        const float4 wmr = pWmR[kb * 64 + c];
        const float4 vr = *reinterpret_cast<const float4*>(&sm[1408 + kb * 4]);
        amR = fmaf(vr.x, wmr.x, amR); amR = fmaf(vr.y, wmr.y, amR);
        amR = fmaf(vr.z, wmr.z, amR); amR = fmaf(vr.w, wmr.w, amR);
      }
#define UPDD(i) hD##i = (1.f - z##i) * hD##i + z##i * tanhf(am##i);
      R11(UPDD)
#undef UPDD
      hR = (1.f - zR_) * hR + zR_ * tanhf(amR);
    }
  }

  // ---------------- scores ----------------
  sm[c] = hR;
#define STASH_O(i) sm[(1 + i) * 64 + c] = hO##i;
  R10(STASH_O)
#undef STASH_O
#define STASH_D(i) sm[(11 + i) * 64 + c] = hD##i;
  R11(STASH_D)
#undef STASH_D

  const int g = c >> 4;    // row-group 0..3
  const int c1 = c & 15;   // hidden-1 column
  float pR = 0.f, pO = 0.f, pD = 0.f;
  for (int rr = g; rr < 22; rr += 4) {
    const float* W1; const float* b1; const float* W2;
    if (rr == 0)      { W1 = W1R; b1 = b1R; W2 = W2R; }
    else if (rr < 11) { W1 = W1O; b1 = b1O; W2 = W2O; }
    else              { W1 = W1D; b1 = b1D; W2 = W2D; }
    float a = b1[c1];
#pragma unroll 8
    for (int kk = 0; kk < 64; ++kk) {
      const int k = (kk + (g << 4)) & 63;  // stagger to dodge LDS bank aliasing
      a = fmaf(sm[rr * 64 + k], W1[k * 16 + c1], a);
    }
    const float t = tanhf(a) * W2[c1];
    if (rr == 0) pR += t;
    else if (rr < 11) pO += t;
    else pD += t;
  }
#pragma unroll
  for (int off = 32; off >= 1; off >>= 1) {
    pR += __shfl_xor(pR, off, 64);
    pO += __shfl_xor(pO, off, 64);
    pD += __shfl_xor(pD, off, 64);
  }
  if (c < 60) {
    out[(size_t)b * 60 + c] = pR * tp[c] + pO * tp[60 + c] + pD * tp[120 + c];
  }
}

extern "C" void kernel_launch(void* const* d_in, const int* in_sizes, int n_in,
                              void* d_out, int out_size, void* d_ws, size_t ws_size,
                              hipStream_t stream) {
  const float* X   = (const float*)d_in[0];
  const float* A   = (const float*)d_in[1];
  const float* WgR = (const float*)d_in[2];
  const float* bgR = (const float*)d_in[3];
  const float* WgO = (const float*)d_in[4];
  const float* bgO = (const float*)d_in[5];
  const float* WgD = (const float*)d_in[6];
  const float* bgD = (const float*)d_in[7];
  const float* WzR = (const float*)d_in[8];
  const float* WrR = (const float*)d_in[9];
  const float* WmR = (const float*)d_in[10];
  const float* bmR = (const float*)d_in[11];
  const float* WzO = (const float*)d_in[12];
  const float* WrO = (const float*)d_in[13];
  const float* WmO = (const float*)d_in[14];
  const float* bmO = (const float*)d_in[15];
  const float* WzD = (const float*)d_in[16];
  const float* WrD = (const float*)d_in[17];
  const float* WmD = (const float*)d_in[18];
  const float* bmD = (const float*)d_in[19];
  const float* W1R = (const float*)d_in[20];
  const float* b1R = (const float*)d_in[21];
  const float* W2R = (const float*)d_in[22];
  const float* W1O = (const float*)d_in[23];
  const float* b1O = (const float*)d_in[24];
  const float* W2O = (const float*)d_in[25];
  const float* W1D = (const float*)d_in[26];
  const float* b1D = (const float*)d_in[27];
  const float* W2D = (const float*)d_in[28];
  const float* Tmp = (const float*)d_in[29];
  const float* GK  = (const float*)d_in[30];
  const float* GRK = (const float*)d_in[31];
  const float* GB  = (const float*)d_in[32];
  const float* WO  = (const float*)d_in[33];
  const int*   IDX = (const int*)d_in[34];

  float* tp = (float*)d_ws;  // 3*60 floats (within the first 1KB)
  char*  ws = (char*)d_ws;
  const int B = in_sizes[0] / 880;

  hipLaunchKernelGGL(temporal_kernel, dim3(1), dim3(64), 0, stream, Tmp, GK, GRK, GB, WO, IDX, tp);
  hipLaunchKernelGGL(prep_kernel, dim3(336), dim3(64), 0, stream,
                     WzR, WrR, WmR, WzO, WrO, WmO, WzD, WrD, WmD, ws);
  hipLaunchKernelGGL(ggnn_main, dim3((B + 3) / 4), dim3(256), 0, stream,
                     X, A, WgR, bgR, WgO, bgO, WgD, bgD,
                     bmR, bmO, bmD,
                     W1R, b1R, W2R, W1O, b1O, W2O, W1D, b1D, W2D,
                     (const char*)ws, (const float*)tp, B, (float*)d_out);
}